// Round 1
// 429.050 us; speedup vs baseline: 1.0483x; 1.0483x over previous
//
#include <hip/hip_runtime.h>
#include <hip/hip_bf16.h>

// Problem constants
#define BB 8
#define TT 2048
#define DD 1024   // d_model
#define FF 1024   // ff dim

typedef __attribute__((ext_vector_type(8))) short bf16x8;
typedef __attribute__((ext_vector_type(4))) float f32x4;
typedef __attribute__((ext_vector_type(4))) short s16x4;

constexpr float kScaleLog2e = 0.03125f * 1.44269504088896340736f;

__device__ __forceinline__ short bf16_bits(float x) {
    __hip_bfloat16 h = __float2bfloat16(x);
    short s;
    __builtin_memcpy(&s, &h, sizeof(short));
    return s;
}

// ---------------------------------------------------------------------------
// Merged f32 -> bf16 convert: seq (8192 blocks) + Wq/Wk/Wv (512 each).
// ---------------------------------------------------------------------------
__global__ __launch_bounds__(256) void cvt_all(
    const float* __restrict__ seq, const float* __restrict__ Wq,
    const float* __restrict__ Wk, const float* __restrict__ Wv,
    short* __restrict__ seqb, short* __restrict__ Wb)
{
    const int bid = blockIdx.x;
    const float* src;
    short* dst;
    int i;
    if (bid < 8192)      { src = seq; dst = seqb;                      i = bid * 256 + threadIdx.x; }
    else if (bid < 8704) { src = Wq;  dst = Wb;                        i = (bid - 8192) * 256 + threadIdx.x; }
    else if (bid < 9216) { src = Wk;  dst = Wb + (size_t)FF * DD;      i = (bid - 8704) * 256 + threadIdx.x; }
    else                 { src = Wv;  dst = Wb + (size_t)2 * FF * DD;  i = (bid - 9216) * 256 + threadIdx.x; }
    f32x4 a = ((const f32x4*)src)[2 * i];
    f32x4 b = ((const f32x4*)src)[2 * i + 1];
    bf16x8 o;
#pragma unroll
    for (int j = 0; j < 4; ++j) { o[j] = bf16_bits(a[j]); o[4 + j] = bf16_bits(b[j]); }
    ((bf16x8*)dst)[i] = o;
}

// ===========================================================================
// 256x256 8-phase bf16 GEMM core (T2 LDS swizzle + T3/T4 counted vmcnt + T5).
//
// Geometry: BM=BN=256, BK=64 (two 32-wide K-halves), 512 thr = 8 waves (2Mx4N),
// per-wave output 128x64 = acc[8][4] f32x4.  LDS: ring of 4 K-half slots per
// operand, slot = 256 rows x 32 k bf16 = 16 KiB; total 128 KiB.
//
// Swizzle (both-sides, rule #21): physical 16B chunk cp = kg ^ ((row>>1)&3).
// Writer: linear LDS dest (global_load_lds lane-contiguous), inverse-swizzled
// GLOBAL source.  Reader: ds_read_b128 at row*64B + cp*16B -> 2 lanes/bank
// (conflict-free).
//
// Stage schedule (one half-slot = 2 global_load_lds/thread per phase):
//   t.P1: A(2t+3)   t.P2: B(2t+3)   t.P3: A(2t+4)   t.P4: B(2t+4)
// Slot h&3 is overwritten >=1 phase after its last read (barrier-separated).
// Counted waits (end of P2 / P4, before closing barrier, never 0 in steady):
//   end-P2: vmcnt(8) -> halves 2t+1 landed (protects P3 reads)
//   end-P4: vmcnt(8) -> halves 2t+2 landed (protects next-tile P1 reads)
// Prologue: stage h=0,1,2 (A,B each; 12 loads), vmcnt(8), barrier.
// Peel: tile T-2 stages P1/P2 only, waits (8,4); tile T-1 no stages, (0,-).
// ===========================================================================
#define SLOT 8192   // shorts per K-half slot

__device__ __forceinline__ void stage2(const short* g0, const short* g1,
                                       short* slot, int lo0, int lo1) {
    __builtin_amdgcn_global_load_lds(
        (const __attribute__((address_space(1))) unsigned int*)g0,
        (__attribute__((address_space(3))) unsigned int*)(slot + lo0), 16, 0, 0);
    __builtin_amdgcn_global_load_lds(
        (const __attribute__((address_space(1))) unsigned int*)g1,
        (__attribute__((address_space(3))) unsigned int*)(slot + lo1), 16, 0, 0);
}

__device__ __forceinline__ void phase_pre() {
    __builtin_amdgcn_s_barrier();
    asm volatile("s_waitcnt lgkmcnt(0)" ::: "memory");
    __builtin_amdgcn_sched_barrier(0);
    __builtin_amdgcn_s_setprio(1);
}

template<int W>
__device__ __forceinline__ void phase_post() {
    __builtin_amdgcn_s_setprio(0);
    __builtin_amdgcn_sched_barrier(0);
    if constexpr (W == 8)      asm volatile("s_waitcnt vmcnt(8)" ::: "memory");
    else if constexpr (W == 4) asm volatile("s_waitcnt vmcnt(4)" ::: "memory");
    else if constexpr (W == 0) asm volatile("s_waitcnt vmcnt(0)" ::: "memory");
    __builtin_amdgcn_s_barrier();
}

template<bool S12, bool S34, int W1, int W2>
__device__ __forceinline__ void tile_body(
    int t, short* As, short* Bs,
    const short* a0, const short* a1, const short* b0, const short* b1,
    int lo0, int lo1, int wm, int wn, int rk, f32x4 (&acc)[8][4])
{
    const short* sA0 = As + ((2 * t) & 3) * SLOT;
    const short* sB0 = Bs + ((2 * t) & 3) * SLOT;
    const short* sA1 = As + ((2 * t + 1) & 3) * SLOT;
    const short* sB1 = Bs + ((2 * t + 1) & 3) * SLOT;

    bf16x8 a[4], b[4];

    // ---- phase 1: k-half 0, M-half 0 (8 ds_reads); stage A(2t+3) ----
#pragma unroll
    for (int m = 0; m < 4; ++m) a[m] = *(const bf16x8*)(sA0 + (wm + m * 16) * 32 + rk);
#pragma unroll
    for (int n = 0; n < 4; ++n) b[n] = *(const bf16x8*)(sB0 + (wn + n * 16) * 32 + rk);
    if constexpr (S12)
        stage2(a0 + (2 * t + 3) * 32, a1 + (2 * t + 3) * 32,
               As + ((2 * t + 3) & 3) * SLOT, lo0, lo1);
    phase_pre();
#pragma unroll
    for (int m = 0; m < 4; ++m)
#pragma unroll
        for (int n = 0; n < 4; ++n)
            acc[m][n] = __builtin_amdgcn_mfma_f32_16x16x32_bf16(a[m], b[n], acc[m][n], 0, 0, 0);
    phase_post<-1>();

    // ---- phase 2: k-half 0, M-half 1 (4 ds_reads); stage B(2t+3); vmcnt W1 ----
#pragma unroll
    for (int m = 0; m < 4; ++m) a[m] = *(const bf16x8*)(sA0 + (wm + 64 + m * 16) * 32 + rk);
    if constexpr (S12)
        stage2(b0 + (2 * t + 3) * 32, b1 + (2 * t + 3) * 32,
               Bs + ((2 * t + 3) & 3) * SLOT, lo0, lo1);
    phase_pre();
#pragma unroll
    for (int m = 0; m < 4; ++m)
#pragma unroll
        for (int n = 0; n < 4; ++n)
            acc[m + 4][n] = __builtin_amdgcn_mfma_f32_16x16x32_bf16(a[m], b[n], acc[m + 4][n], 0, 0, 0);
    phase_post<W1>();

    // ---- phase 3: k-half 1, M-half 0 (8 ds_reads); stage A(2t+4) ----
#pragma unroll
    for (int m = 0; m < 4; ++m) a[m] = *(const bf16x8*)(sA1 + (wm + m * 16) * 32 + rk);
#pragma unroll
    for (int n = 0; n < 4; ++n) b[n] = *(const bf16x8*)(sB1 + (wn + n * 16) * 32 + rk);
    if constexpr (S34)
        stage2(a0 + (2 * t + 4) * 32, a1 + (2 * t + 4) * 32,
               As + ((2 * t + 4) & 3) * SLOT, lo0, lo1);
    phase_pre();
#pragma unroll
    for (int m = 0; m < 4; ++m)
#pragma unroll
        for (int n = 0; n < 4; ++n)
            acc[m][n] = __builtin_amdgcn_mfma_f32_16x16x32_bf16(a[m], b[n], acc[m][n], 0, 0, 0);
    phase_post<-1>();

    // ---- phase 4: k-half 1, M-half 1 (4 ds_reads); stage B(2t+4); vmcnt W2 ----
#pragma unroll
    for (int m = 0; m < 4; ++m) a[m] = *(const bf16x8*)(sA1 + (wm + 64 + m * 16) * 32 + rk);
    if constexpr (S34)
        stage2(b0 + (2 * t + 4) * 32, b1 + (2 * t + 4) * 32,
               Bs + ((2 * t + 4) & 3) * SLOT, lo0, lo1);
    phase_pre();
#pragma unroll
    for (int m = 0; m < 4; ++m)
#pragma unroll
        for (int n = 0; n < 4; ++n)
            acc[m + 4][n] = __builtin_amdgcn_mfma_f32_16x16x32_bf16(a[m], b[n], acc[m + 4][n], 0, 0, 0);
    phase_post<W2>();
}

__device__ __forceinline__ void gemm256(
    const short* __restrict__ A, int lda, int m0,
    const short* __restrict__ B, int ldb, int n0,
    int T, short* As, short* Bs, f32x4 (&acc)[8][4])
{
    const int tid  = threadIdx.x;
    const int lane = tid & 63;
    const int w    = tid >> 6;
    const int wm   = (w >> 2) * 128;
    const int wn   = (w & 3) * 64;
    const int r    = lane & 15;
    const int qd   = lane >> 4;
    // reader swizzle: cp = qd ^ ((row>>1)&3); row = 16*frag + r -> depends on r only
    const int rk   = r * 32 + (qd ^ ((r >> 1) & 3)) * 8;

    // stage-source precompute (per-thread constants): 16B chunk s = w*128+j*64+lane
    const int s0   = w * 128 + lane, s1 = s0 + 64;
    const int row0 = s0 >> 2,  row1 = s1 >> 2;
    const int cl0  = (s0 & 3) ^ ((row0 >> 1) & 3);
    const int cl1  = (s1 & 3) ^ ((row1 >> 1) & 3);
    const short* a0 = A + (size_t)(m0 + row0) * lda + cl0 * 8;
    const short* a1 = A + (size_t)(m0 + row1) * lda + cl1 * 8;
    const short* b0 = B + (size_t)(n0 + row0) * ldb + cl0 * 8;
    const short* b1 = B + (size_t)(n0 + row1) * ldb + cl1 * 8;
    const int lo0 = s0 * 8, lo1 = s1 * 8;

    // prologue: halves 0,1,2 of A and B (12 loads); A0/B0 landed after vmcnt(8)
    stage2(a0,      a1,      As,            lo0, lo1);
    stage2(b0,      b1,      Bs,            lo0, lo1);
    stage2(a0 + 32, a1 + 32, As + SLOT,     lo0, lo1);
    stage2(b0 + 32, b1 + 32, Bs + SLOT,     lo0, lo1);
    stage2(a0 + 64, a1 + 64, As + 2 * SLOT, lo0, lo1);
    stage2(b0 + 64, b1 + 64, Bs + 2 * SLOT, lo0, lo1);
    asm volatile("s_waitcnt vmcnt(8)" ::: "memory");
    __builtin_amdgcn_s_barrier();

    for (int t = 0; t < T - 2; ++t)
        tile_body<true, true, 8, 8>(t, As, Bs, a0, a1, b0, b1, lo0, lo1, wm, wn, rk, acc);
    tile_body<true,  false, 8, 4>(T - 2, As, Bs, a0, a1, b0, b1, lo0, lo1, wm, wn, rk, acc);
    tile_body<false, false, 0, -1>(T - 1, As, Bs, a0, a1, b0, b1, lo0, lo1, wm, wn, rk, acc);
}

// ---------------------------------------------------------------------------
// Kernel 1: q/k = seqb @ Wb^T + bias (bf16 out); v transposed vT[b][f][t].
// Grid 768 = 64 mt x 4 nt x 3 proj, XCD-chunked: each XCD owns 8 contiguous
// mt-stripes (A-panel L2 reuse across the 12 (nt,proj) blocks).
// ---------------------------------------------------------------------------
__global__ __launch_bounds__(512, 2) void qkv256(
    const short* __restrict__ seqb, const short* __restrict__ Wb,
    const float* __restrict__ bq, const float* __restrict__ bk,
    const float* __restrict__ bv,
    __hip_bfloat16* __restrict__ q, __hip_bfloat16* __restrict__ k,
    __hip_bfloat16* __restrict__ vT)
{
    __shared__ short As[4 * SLOT], Bs[4 * SLOT];
    const int bid  = blockIdx.x;
    const int id2  = (bid & 7) * 96 + (bid >> 3);   // bijective (768 % 8 == 0)
    const int mt   = id2 / 12;
    const int rest = id2 - mt * 12;
    const int nt   = rest & 3;
    const int proj = rest >> 2;

    const short* W    = Wb + (size_t)proj * FF * DD;
    const float* bias = proj == 0 ? bq : (proj == 1 ? bk : bv);

    f32x4 acc[8][4];
#pragma unroll
    for (int m = 0; m < 8; ++m)
#pragma unroll
        for (int n = 0; n < 4; ++n) acc[m][n] = (f32x4){0.f, 0.f, 0.f, 0.f};

    gemm256(seqb, DD, mt * 256, W, DD, nt * 256, DD / 64, As, Bs, acc);

    const int lane = threadIdx.x & 63;
    const int w    = threadIdx.x >> 6;
    const int wm   = (w >> 2) * 128;
    const int wn   = (w & 3) * 64;
    const int r    = lane & 15;
    const int qd   = lane >> 4;
    const int row_base = mt * 256 + wm + qd * 4;
    const int col_base = nt * 256 + wn + r;

    if (proj < 2) {
        __hip_bfloat16* dst = (proj == 0) ? q : k;
#pragma unroll
        for (int nf = 0; nf < 4; ++nf) {
            const int col = col_base + nf * 16;
            const float bv_ = bias[col];
#pragma unroll
            for (int mf = 0; mf < 8; ++mf)
#pragma unroll
                for (int i = 0; i < 4; ++i)
                    dst[(size_t)(row_base + mf * 16 + i) * FF + col] =
                        __float2bfloat16(acc[mf][nf][i] + bv_);
        }
    } else {
        // transposed V: lane's 4 regs = 4 consecutive t -> 8B packed store
#pragma unroll
        for (int mf = 0; mf < 8; ++mf) {
            const int rowg = row_base + mf * 16;
            const int b_   = rowg >> 11;
            const int t_   = rowg & 2047;
            __hip_bfloat16* vb = vT + (size_t)b_ * FF * TT;
#pragma unroll
            for (int nf = 0; nf < 4; ++nf) {
                const int col = col_base + nf * 16;
                const float bvv = bias[col];
                s16x4 pack;
#pragma unroll
                for (int i = 0; i < 4; ++i) pack[i] = bf16_bits(acc[mf][nf][i] + bvv);
                *(s16x4*)(vb + (size_t)col * TT + t_) = pack;
            }
        }
    }
}

// ---------------------------------------------------------------------------
// Kernel 2: P[b][t][s] = exp(scale*q.k) bf16 (unnormalized), Z[b][t] += rowsum.
// Grid 512 = 8 b x 8 tt x 8 st (st fastest); XCD-chunked: one b per XCD.
// ---------------------------------------------------------------------------
__global__ __launch_bounds__(512, 2) void score256(
    const __hip_bfloat16* __restrict__ q, const __hip_bfloat16* __restrict__ k,
    __hip_bfloat16* __restrict__ P, float* __restrict__ Z)
{
    __shared__ short As[4 * SLOT], Bs[4 * SLOT];
    const int bid = blockIdx.x;
    const int id2 = (bid & 7) * 64 + (bid >> 3);
    const int b   = id2 >> 6;
    const int tt  = (id2 >> 3) & 7;
    const int st  = id2 & 7;

    const short* qb = (const short*)q + (size_t)b * TT * FF;
    const short* kb = (const short*)k + (size_t)b * TT * FF;

    f32x4 acc[8][4];
#pragma unroll
    for (int m = 0; m < 8; ++m)
#pragma unroll
        for (int n = 0; n < 4; ++n) acc[m][n] = (f32x4){0.f, 0.f, 0.f, 0.f};

    gemm256(qb, FF, tt * 256, kb, FF, st * 256, FF / 64, As, Bs, acc);

    const int lane = threadIdx.x & 63;
    const int w    = threadIdx.x >> 6;
    const int wm   = (w >> 2) * 128;
    const int wn   = (w & 3) * 64;
    const int r    = lane & 15;
    const int qd   = lane >> 4;
    const int row_base = tt * 256 + wm + qd * 4;
    const int col_base = st * 256 + wn + r;

    __hip_bfloat16* Pb = P + (size_t)b * TT * TT;
    float* Zb = Z + b * TT;

    float rs[8][4];
#pragma unroll
    for (int mf = 0; mf < 8; ++mf)
#pragma unroll
        for (int i = 0; i < 4; ++i) rs[mf][i] = 0.f;

#pragma unroll
    for (int mf = 0; mf < 8; ++mf)
#pragma unroll
        for (int nf = 0; nf < 4; ++nf) {
            const int col = col_base + nf * 16;
#pragma unroll
            for (int i = 0; i < 4; ++i) {
                const float e = exp2f(acc[mf][nf][i] * kScaleLog2e);
                const __hip_bfloat16 eb = __float2bfloat16(e);
                rs[mf][i] += __bfloat162float(eb);
                Pb[(size_t)(row_base + mf * 16 + i) * TT + col] = eb;
            }
        }
#pragma unroll
    for (int off = 1; off < 16; off <<= 1)
#pragma unroll
        for (int mf = 0; mf < 8; ++mf)
#pragma unroll
            for (int i = 0; i < 4; ++i) rs[mf][i] += __shfl_xor(rs[mf][i], off, 64);
    if (r == 0) {
#pragma unroll
        for (int mf = 0; mf < 8; ++mf)
#pragma unroll
            for (int i = 0; i < 4; ++i)
                atomicAdd(&Zb[row_base + mf * 16 + i], rs[mf][i]);
    }
}

// ---------------------------------------------------------------------------
// Kernel 3: out[b][t][f] = (P @ V)/Z via vT.  Grid 256 = 8 b x 8 tt x 4 ft.
// ---------------------------------------------------------------------------
__global__ __launch_bounds__(512, 2) void pv256(
    const __hip_bfloat16* __restrict__ P, const __hip_bfloat16* __restrict__ vT,
    const float* __restrict__ Z, float* __restrict__ out)
{
    __shared__ short As[4 * SLOT], Bs[4 * SLOT];
    const int bid = blockIdx.x;
    const int id2 = (bid & 7) * 32 + (bid >> 3);
    const int b   = id2 >> 5;
    const int tt  = (id2 >> 2) & 7;
    const int ft  = id2 & 3;

    const short* Pb = (const short*)P + (size_t)b * TT * TT;
    const short* vb = (const short*)vT + (size_t)b * FF * TT;

    f32x4 acc[8][4];
#pragma unroll
    for (int m = 0; m < 8; ++m)
#pragma unroll
        for (int n = 0; n < 4; ++n) acc[m][n] = (f32x4){0.f, 0.f, 0.f, 0.f};

    gemm256(Pb, TT, tt * 256, vb, TT, ft * 256, TT / 64, As, Bs, acc);

    const int lane = threadIdx.x & 63;
    const int w    = threadIdx.x >> 6;
    const int wm   = (w >> 2) * 128;
    const int wn   = (w & 3) * 64;
    const int r    = lane & 15;
    const int qd   = lane >> 4;
    const int row_base = tt * 256 + wm + qd * 4;
    const int col_base = ft * 256 + wn + r;

    const float* Zb = Z + b * TT;
    float* ob = out + (size_t)b * TT * FF;

#pragma unroll
    for (int mf = 0; mf < 8; ++mf) {
        float rz[4];
#pragma unroll
        for (int i = 0; i < 4; ++i) rz[i] = 1.0f / Zb[row_base + mf * 16 + i];
#pragma unroll
        for (int nf = 0; nf < 4; ++nf) {
            const int col = col_base + nf * 16;
#pragma unroll
            for (int i = 0; i < 4; ++i)
                ob[(size_t)(row_base + mf * 16 + i) * FF + col] = acc[mf][nf][i] * rz[i];
        }
    }
}

// ---------------------------------------------------------------------------
extern "C" void kernel_launch(void* const* d_in, const int* in_sizes, int n_in,
                              void* d_out, int out_size, void* d_ws, size_t ws_size,
                              hipStream_t stream) {
    const float* seq = (const float*)d_in[0];
    const float* Wq  = (const float*)d_in[1];
    const float* bq  = (const float*)d_in[2];
    const float* Wk  = (const float*)d_in[3];
    const float* bk  = (const float*)d_in[4];
    const float* Wv  = (const float*)d_in[5];
    const float* bv  = (const float*)d_in[6];
    float* out = (float*)d_out;
    char* ws = (char*)d_ws;

    // Workspace layout (unchanged):
    //   q   : 32 MiB @ 0
    //   k   : 32 MiB @ 33554432
    //   vT  : 32 MiB @ 67108864
    //   P   : 64 MiB @ 100663296   (seqb [32 MiB] + Wb [6 MiB] alias P;
    //                               both dead before score writes P)
    //   Z   : 64 KiB @ 167772160
    const size_t MB32 = 33554432;
    __hip_bfloat16* q   = (__hip_bfloat16*)(ws);
    __hip_bfloat16* k   = (__hip_bfloat16*)(ws + MB32);
    __hip_bfloat16* vT  = (__hip_bfloat16*)(ws + 2 * MB32);
    __hip_bfloat16* P   = (__hip_bfloat16*)(ws + 3 * MB32);
    float*          Z   = (float*)(ws + 3 * MB32 + (size_t)67108864);
    short*          seqb = (short*)P;
    short*          Wb   = (short*)((char*)P + MB32);

    hipMemsetAsync(Z, 0, (size_t)BB * TT * sizeof(float), stream);

    cvt_all<<<9728, 256, 0, stream>>>(seq, Wq, Wk, Wv, seqb, Wb);
    qkv256<<<768, 512, 0, stream>>>(seqb, Wb, bq, bk, bv, q, k, vT);
    score256<<<BB * 64, 512, 0, stream>>>(q, k, P, Z);
    pv256<<<BB * 32, 512, 0, stream>>>(P, vT, Z, out);
}

// Round 2
// 408.429 us; speedup vs baseline: 1.1013x; 1.0505x over previous
//
#include <hip/hip_runtime.h>
#include <hip/hip_bf16.h>

// Problem constants
#define BB 8
#define TT 2048
#define DD 1024   // d_model
#define FF 1024   // ff dim

typedef __attribute__((ext_vector_type(8))) short bf16x8;
typedef __attribute__((ext_vector_type(4))) float f32x4;
typedef __attribute__((ext_vector_type(4))) short s16x4;

constexpr float kScaleLog2e = 0.03125f * 1.44269504088896340736f;

__device__ __forceinline__ short bf16_bits(float x) {
    __hip_bfloat16 h = __float2bfloat16(x);
    short s;
    __builtin_memcpy(&s, &h, sizeof(short));
    return s;
}

// ---------------------------------------------------------------------------
// Merged f32 -> bf16 convert: seq (8192 blocks) + Wq/Wk/Wv (512 each).
// ---------------------------------------------------------------------------
__global__ __launch_bounds__(256) void cvt_all(
    const float* __restrict__ seq, const float* __restrict__ Wq,
    const float* __restrict__ Wk, const float* __restrict__ Wv,
    short* __restrict__ seqb, short* __restrict__ Wb)
{
    const int bid = blockIdx.x;
    const float* src;
    short* dst;
    int i;
    if (bid < 8192)      { src = seq; dst = seqb;                      i = bid * 256 + threadIdx.x; }
    else if (bid < 8704) { src = Wq;  dst = Wb;                        i = (bid - 8192) * 256 + threadIdx.x; }
    else if (bid < 9216) { src = Wk;  dst = Wb + (size_t)FF * DD;      i = (bid - 8704) * 256 + threadIdx.x; }
    else                 { src = Wv;  dst = Wb + (size_t)2 * FF * DD;  i = (bid - 9216) * 256 + threadIdx.x; }
    f32x4 a = ((const f32x4*)src)[2 * i];
    f32x4 b = ((const f32x4*)src)[2 * i + 1];
    bf16x8 o;
#pragma unroll
    for (int j = 0; j < 4; ++j) { o[j] = bf16_bits(a[j]); o[4 + j] = bf16_bits(b[j]); }
    ((bf16x8*)dst)[i] = o;
}

// ===========================================================================
// 256x256 bf16 GEMM core — 4 compute phases per K-tile (BK=64), but only
// TWO s_barrier per K-tile (round-1 change; was 8).  Per-wave counted
// lgkmcnt(0) before each MFMA cluster lets the 2 waves/SIMD slip so one
// wave's MFMA covers the other's LDS wait (previously 8 lockstep barriers
// serialized LDS-exec with MFMA across the whole CU -> 6955 cyc/K-tile vs
// 3602 serial model).
//
// Hazard audit (instruction-counted vmcnt; stage2 = 2 global_load_lds):
//   window P1/P2 of tile t: ds_reads slot (2t)&3;   gloads -> (2t+3)&3  (!=)
//   window P3/P4 of tile t: ds_reads slot (2t+1)&3; gloads -> (2t+4)&3  (!=)
//   mid-barrier (after P2): vmcnt(8) -> half 2t+1 landed (12 in flight,
//     oldest 4 = A/B(2t+1)); publishes slot for P3 reads; also all waves'
//     reads of slot (2t)&3 retired (own lgkmcnt(0) before Q1) -> safe for
//     P3/P4 gloads into (2t)&3 == (2t+4)&3.
//   end-barrier (after P4): vmcnt(8) -> half 2t+2 landed; slot (2t+1)&3
//     reads retired -> safe for next tile's gloads.
// Accumulation order unchanged -> bit-identical result vs round 0.
//
// Swizzle (both-sides, rule #21): physical 16B chunk cp = kg ^ ((row>>1)&3);
// writer = linear LDS dest + inverse-swizzled global source; reader =
// swizzled ds_read_b128 (SQ_LDS_BANK_CONFLICT measured 0).
// ===========================================================================
#define SLOT 8192   // shorts per K-half slot (256 rows x 32 k)

__device__ __forceinline__ void stage2(const short* g0, const short* g1,
                                       short* slot, int lo0, int lo1) {
    __builtin_amdgcn_global_load_lds(
        (const __attribute__((address_space(1))) unsigned int*)g0,
        (__attribute__((address_space(3))) unsigned int*)(slot + lo0), 16, 0, 0);
    __builtin_amdgcn_global_load_lds(
        (const __attribute__((address_space(1))) unsigned int*)g1,
        (__attribute__((address_space(3))) unsigned int*)(slot + lo1), 16, 0, 0);
}

// counted-vmcnt publish barrier; sched_barrier pins ds_reads/gloads on the
// correct side (publish + overwrite-protect fence).
template<int W>
__device__ __forceinline__ void tile_barrier() {
    if constexpr (W == 8)      asm volatile("s_waitcnt vmcnt(8)" ::: "memory");
    else if constexpr (W == 4) asm volatile("s_waitcnt vmcnt(4)" ::: "memory");
    else if constexpr (W == 0) asm volatile("s_waitcnt vmcnt(0)" ::: "memory");
    __builtin_amdgcn_s_barrier();
    __builtin_amdgcn_sched_barrier(0);
}

// own-reads-landed gate before an MFMA cluster (rule #18: sched_barrier
// after inline-asm lgkmcnt, else MFMA hoists past it).
__device__ __forceinline__ void lgkm_gate() {
    asm volatile("s_waitcnt lgkmcnt(0)" ::: "memory");
    __builtin_amdgcn_sched_barrier(0);
}

template<bool S12, bool S34, int WMID, int WEND>
__device__ __forceinline__ void tile_body(
    int t, short* As, short* Bs,
    const short* a0, const short* a1, const short* b0, const short* b1,
    int lo0, int lo1, int wm, int wn, int rk, f32x4 (&acc)[8][4])
{
    const short* sA0 = As + ((2 * t) & 3) * SLOT;
    const short* sB0 = Bs + ((2 * t) & 3) * SLOT;
    const short* sA1 = As + ((2 * t + 1) & 3) * SLOT;
    const short* sB1 = Bs + ((2 * t + 1) & 3) * SLOT;

    bf16x8 a[4], b[4];

    // ---- P1: k-half 0, M-half 0; stage A(2t+3) ----
#pragma unroll
    for (int m = 0; m < 4; ++m) a[m] = *(const bf16x8*)(sA0 + (wm + m * 16) * 32 + rk);
#pragma unroll
    for (int n = 0; n < 4; ++n) b[n] = *(const bf16x8*)(sB0 + (wn + n * 16) * 32 + rk);
    if constexpr (S12)
        stage2(a0 + (2 * t + 3) * 32, a1 + (2 * t + 3) * 32,
               As + ((2 * t + 3) & 3) * SLOT, lo0, lo1);
    lgkm_gate();
    __builtin_amdgcn_s_setprio(1);
#pragma unroll
    for (int m = 0; m < 4; ++m)
#pragma unroll
        for (int n = 0; n < 4; ++n)
            acc[m][n] = __builtin_amdgcn_mfma_f32_16x16x32_bf16(a[m], b[n], acc[m][n], 0, 0, 0);
    __builtin_amdgcn_s_setprio(0);

    // ---- P2: k-half 0, M-half 1 (b[] reused); stage B(2t+3) ----
#pragma unroll
    for (int m = 0; m < 4; ++m) a[m] = *(const bf16x8*)(sA0 + (wm + 64 + m * 16) * 32 + rk);
    if constexpr (S12)
        stage2(b0 + (2 * t + 3) * 32, b1 + (2 * t + 3) * 32,
               Bs + ((2 * t + 3) & 3) * SLOT, lo0, lo1);
    lgkm_gate();
    __builtin_amdgcn_s_setprio(1);
#pragma unroll
    for (int m = 0; m < 4; ++m)
#pragma unroll
        for (int n = 0; n < 4; ++n)
            acc[m + 4][n] = __builtin_amdgcn_mfma_f32_16x16x32_bf16(a[m], b[n], acc[m + 4][n], 0, 0, 0);
    __builtin_amdgcn_s_setprio(0);

    tile_barrier<WMID>();   // publish h(2t+1); slot (2t)&3 now reusable

    // ---- P3: k-half 1, M-half 0; stage A(2t+4) ----
#pragma unroll
    for (int m = 0; m < 4; ++m) a[m] = *(const bf16x8*)(sA1 + (wm + m * 16) * 32 + rk);
#pragma unroll
    for (int n = 0; n < 4; ++n) b[n] = *(const bf16x8*)(sB1 + (wn + n * 16) * 32 + rk);
    if constexpr (S34)
        stage2(a0 + (2 * t + 4) * 32, a1 + (2 * t + 4) * 32,
               As + ((2 * t + 4) & 3) * SLOT, lo0, lo1);
    lgkm_gate();
    __builtin_amdgcn_s_setprio(1);
#pragma unroll
    for (int m = 0; m < 4; ++m)
#pragma unroll
        for (int n = 0; n < 4; ++n)
            acc[m][n] = __builtin_amdgcn_mfma_f32_16x16x32_bf16(a[m], b[n], acc[m][n], 0, 0, 0);
    __builtin_amdgcn_s_setprio(0);

    // ---- P4: k-half 1, M-half 1 (b[] reused); stage B(2t+4) ----
#pragma unroll
    for (int m = 0; m < 4; ++m) a[m] = *(const bf16x8*)(sA1 + (wm + 64 + m * 16) * 32 + rk);
    if constexpr (S34)
        stage2(b0 + (2 * t + 4) * 32, b1 + (2 * t + 4) * 32,
               Bs + ((2 * t + 4) & 3) * SLOT, lo0, lo1);
    lgkm_gate();
    __builtin_amdgcn_s_setprio(1);
#pragma unroll
    for (int m = 0; m < 4; ++m)
#pragma unroll
        for (int n = 0; n < 4; ++n)
            acc[m + 4][n] = __builtin_amdgcn_mfma_f32_16x16x32_bf16(a[m], b[n], acc[m + 4][n], 0, 0, 0);
    __builtin_amdgcn_s_setprio(0);

    if constexpr (WEND >= 0)
        tile_barrier<WEND>();   // publish h(2t+2); slot (2t+1)&3 reusable
}

__device__ __forceinline__ void gemm256(
    const short* __restrict__ A, int lda, int m0,
    const short* __restrict__ B, int ldb, int n0,
    int T, short* As, short* Bs, f32x4 (&acc)[8][4])
{
    const int tid  = threadIdx.x;
    const int lane = tid & 63;
    const int w    = tid >> 6;
    const int wm   = (w >> 2) * 128;
    const int wn   = (w & 3) * 64;
    const int r    = lane & 15;
    const int qd   = lane >> 4;
    // reader swizzle: cp = qd ^ ((row>>1)&3); row = 16*frag + r -> depends on r only
    const int rk   = r * 32 + (qd ^ ((r >> 1) & 3)) * 8;

    // stage-source precompute: 16B chunk s = w*128 + j*64 + lane
    const int s0   = w * 128 + lane, s1 = s0 + 64;
    const int row0 = s0 >> 2,  row1 = s1 >> 2;
    const int cl0  = (s0 & 3) ^ ((row0 >> 1) & 3);
    const int cl1  = (s1 & 3) ^ ((row1 >> 1) & 3);
    const short* a0 = A + (size_t)(m0 + row0) * lda + cl0 * 8;
    const short* a1 = A + (size_t)(m0 + row1) * lda + cl1 * 8;
    const short* b0 = B + (size_t)(n0 + row0) * ldb + cl0 * 8;
    const short* b1 = B + (size_t)(n0 + row1) * ldb + cl1 * 8;
    const int lo0 = s0 * 8, lo1 = s1 * 8;

    // prologue: halves 0,1,2 of A and B (12 loads); vmcnt(8) -> h0 landed
    stage2(a0,      a1,      As,            lo0, lo1);
    stage2(b0,      b1,      Bs,            lo0, lo1);
    stage2(a0 + 32, a1 + 32, As + SLOT,     lo0, lo1);
    stage2(b0 + 32, b1 + 32, Bs + SLOT,     lo0, lo1);
    stage2(a0 + 64, a1 + 64, As + 2 * SLOT, lo0, lo1);
    stage2(b0 + 64, b1 + 64, Bs + 2 * SLOT, lo0, lo1);
    tile_barrier<8>();

    for (int t = 0; t < T - 2; ++t)
        tile_body<true, true, 8, 8>(t, As, Bs, a0, a1, b0, b1, lo0, lo1, wm, wn, rk, acc);
    // T-2: stages only h(2T-1) in P1/P2; end needs h(2T-2): vmcnt(4)
    tile_body<true,  false, 8, 4>(T - 2, As, Bs, a0, a1, b0, b1, lo0, lo1, wm, wn, rk, acc);
    // T-1: no stages; mid publishes h(2T-1) via vmcnt(0); no end barrier
    tile_body<false, false, 0, -1>(T - 1, As, Bs, a0, a1, b0, b1, lo0, lo1, wm, wn, rk, acc);
}

// ---------------------------------------------------------------------------
// Kernel 1: q/k = seqb @ Wb^T + bias (bf16 out); v transposed vT[b][f][t].
// Grid 768 = 64 mt x 4 nt x 3 proj, XCD-chunked.
// ---------------------------------------------------------------------------
__global__ __launch_bounds__(512, 2) void qkv256(
    const short* __restrict__ seqb, const short* __restrict__ Wb,
    const float* __restrict__ bq, const float* __restrict__ bk,
    const float* __restrict__ bv,
    __hip_bfloat16* __restrict__ q, __hip_bfloat16* __restrict__ k,
    __hip_bfloat16* __restrict__ vT)
{
    __shared__ short As[4 * SLOT], Bs[4 * SLOT];
    const int bid  = blockIdx.x;
    const int id2  = (bid & 7) * 96 + (bid >> 3);   // bijective (768 % 8 == 0)
    const int mt   = id2 / 12;
    const int rest = id2 - mt * 12;
    const int nt   = rest & 3;
    const int proj = rest >> 2;

    const short* W    = Wb + (size_t)proj * FF * DD;
    const float* bias = proj == 0 ? bq : (proj == 1 ? bk : bv);

    f32x4 acc[8][4];
#pragma unroll
    for (int m = 0; m < 8; ++m)
#pragma unroll
        for (int n = 0; n < 4; ++n) acc[m][n] = (f32x4){0.f, 0.f, 0.f, 0.f};

    gemm256(seqb, DD, mt * 256, W, DD, nt * 256, DD / 64, As, Bs, acc);

    const int lane = threadIdx.x & 63;
    const int w    = threadIdx.x >> 6;
    const int wm   = (w >> 2) * 128;
    const int wn   = (w & 3) * 64;
    const int r    = lane & 15;
    const int qd   = lane >> 4;
    const int row_base = mt * 256 + wm + qd * 4;
    const int col_base = nt * 256 + wn + r;

    if (proj < 2) {
        __hip_bfloat16* dst = (proj == 0) ? q : k;
#pragma unroll
        for (int nf = 0; nf < 4; ++nf) {
            const int col = col_base + nf * 16;
            const float bv_ = bias[col];
#pragma unroll
            for (int mf = 0; mf < 8; ++mf)
#pragma unroll
                for (int i = 0; i < 4; ++i)
                    dst[(size_t)(row_base + mf * 16 + i) * FF + col] =
                        __float2bfloat16(acc[mf][nf][i] + bv_);
        }
    } else {
        // transposed V: lane's 4 regs = 4 consecutive t -> 8B packed store
#pragma unroll
        for (int mf = 0; mf < 8; ++mf) {
            const int rowg = row_base + mf * 16;
            const int b_   = rowg >> 11;
            const int t_   = rowg & 2047;
            __hip_bfloat16* vb = vT + (size_t)b_ * FF * TT;
#pragma unroll
            for (int nf = 0; nf < 4; ++nf) {
                const int col = col_base + nf * 16;
                const float bvv = bias[col];
                s16x4 pack;
#pragma unroll
                for (int i = 0; i < 4; ++i) pack[i] = bf16_bits(acc[mf][nf][i] + bvv);
                *(s16x4*)(vb + (size_t)col * TT + t_) = pack;
            }
        }
    }
}

// ---------------------------------------------------------------------------
// Kernel 2: P[b][t][s] = exp(scale*q.k) bf16 (unnormalized), Z[b][t] += rowsum.
// Grid 512 = 8 b x 8 tt x 8 st (st fastest); XCD-chunked.
// ---------------------------------------------------------------------------
__global__ __launch_bounds__(512, 2) void score256(
    const __hip_bfloat16* __restrict__ q, const __hip_bfloat16* __restrict__ k,
    __hip_bfloat16* __restrict__ P, float* __restrict__ Z)
{
    __shared__ short As[4 * SLOT], Bs[4 * SLOT];
    const int bid = blockIdx.x;
    const int id2 = (bid & 7) * 64 + (bid >> 3);
    const int b   = id2 >> 6;
    const int tt  = (id2 >> 3) & 7;
    const int st  = id2 & 7;

    const short* qb = (const short*)q + (size_t)b * TT * FF;
    const short* kb = (const short*)k + (size_t)b * TT * FF;

    f32x4 acc[8][4];
#pragma unroll
    for (int m = 0; m < 8; ++m)
#pragma unroll
        for (int n = 0; n < 4; ++n) acc[m][n] = (f32x4){0.f, 0.f, 0.f, 0.f};

    gemm256(qb, FF, tt * 256, kb, FF, st * 256, FF / 64, As, Bs, acc);

    const int lane = threadIdx.x & 63;
    const int w    = threadIdx.x >> 6;
    const int wm   = (w >> 2) * 128;
    const int wn   = (w & 3) * 64;
    const int r    = lane & 15;
    const int qd   = lane >> 4;
    const int row_base = tt * 256 + wm + qd * 4;
    const int col_base = st * 256 + wn + r;

    __hip_bfloat16* Pb = P + (size_t)b * TT * TT;
    float* Zb = Z + b * TT;

    float rs[8][4];
#pragma unroll
    for (int mf = 0; mf < 8; ++mf)
#pragma unroll
        for (int i = 0; i < 4; ++i) rs[mf][i] = 0.f;

#pragma unroll
    for (int mf = 0; mf < 8; ++mf)
#pragma unroll
        for (int nf = 0; nf < 4; ++nf) {
            const int col = col_base + nf * 16;
#pragma unroll
            for (int i = 0; i < 4; ++i) {
                const float e = exp2f(acc[mf][nf][i] * kScaleLog2e);
                const __hip_bfloat16 eb = __float2bfloat16(e);
                rs[mf][i] += __bfloat162float(eb);
                Pb[(size_t)(row_base + mf * 16 + i) * TT + col] = eb;
            }
        }
#pragma unroll
    for (int off = 1; off < 16; off <<= 1)
#pragma unroll
        for (int mf = 0; mf < 8; ++mf)
#pragma unroll
            for (int i = 0; i < 4; ++i) rs[mf][i] += __shfl_xor(rs[mf][i], off, 64);
    if (r == 0) {
#pragma unroll
        for (int mf = 0; mf < 8; ++mf)
#pragma unroll
            for (int i = 0; i < 4; ++i)
                atomicAdd(&Zb[row_base + mf * 16 + i], rs[mf][i]);
    }
}

// ---------------------------------------------------------------------------
// Kernel 3: out[b][t][f] = (P @ V)/Z via vT.  Grid 256 = 8 b x 8 tt x 4 ft.
// ---------------------------------------------------------------------------
__global__ __launch_bounds__(512, 2) void pv256(
    const __hip_bfloat16* __restrict__ P, const __hip_bfloat16* __restrict__ vT,
    const float* __restrict__ Z, float* __restrict__ out)
{
    __shared__ short As[4 * SLOT], Bs[4 * SLOT];
    const int bid = blockIdx.x;
    const int id2 = (bid & 7) * 32 + (bid >> 3);
    const int b   = id2 >> 5;
    const int tt  = (id2 >> 2) & 7;
    const int ft  = id2 & 3;

    const short* Pb = (const short*)P + (size_t)b * TT * TT;
    const short* vb = (const short*)vT + (size_t)b * FF * TT;

    f32x4 acc[8][4];
#pragma unroll
    for (int m = 0; m < 8; ++m)
#pragma unroll
        for (int n = 0; n < 4; ++n) acc[m][n] = (f32x4){0.f, 0.f, 0.f, 0.f};

    gemm256(Pb, TT, tt * 256, vb, TT, ft * 256, TT / 64, As, Bs, acc);

    const int lane = threadIdx.x & 63;
    const int w    = threadIdx.x >> 6;
    const int wm   = (w >> 2) * 128;
    const int wn   = (w & 3) * 64;
    const int r    = lane & 15;
    const int qd   = lane >> 4;
    const int row_base = tt * 256 + wm + qd * 4;
    const int col_base = ft * 256 + wn + r;

    const float* Zb = Z + b * TT;
    float* ob = out + (size_t)b * TT * FF;

#pragma unroll
    for (int mf = 0; mf < 8; ++mf) {
        float rz[4];
#pragma unroll
        for (int i = 0; i < 4; ++i) rz[i] = 1.0f / Zb[row_base + mf * 16 + i];
#pragma unroll
        for (int nf = 0; nf < 4; ++nf) {
            const int col = col_base + nf * 16;
#pragma unroll
            for (int i = 0; i < 4; ++i)
                ob[(size_t)(row_base + mf * 16 + i) * FF + col] = acc[mf][nf][i] * rz[i];
        }
    }
}

// ---------------------------------------------------------------------------
extern "C" void kernel_launch(void* const* d_in, const int* in_sizes, int n_in,
                              void* d_out, int out_size, void* d_ws, size_t ws_size,
                              hipStream_t stream) {
    const float* seq = (const float*)d_in[0];
    const float* Wq  = (const float*)d_in[1];
    const float* bq  = (const float*)d_in[2];
    const float* Wk  = (const float*)d_in[3];
    const float* bk  = (const float*)d_in[4];
    const float* Wv  = (const float*)d_in[5];
    const float* bv  = (const float*)d_in[6];
    float* out = (float*)d_out;
    char* ws = (char*)d_ws;

    // Workspace layout (unchanged):
    //   q   : 32 MiB @ 0
    //   k   : 32 MiB @ 33554432
    //   vT  : 32 MiB @ 67108864
    //   P   : 64 MiB @ 100663296   (seqb [32 MiB] + Wb [6 MiB] alias P;
    //                               both dead before score writes P)
    //   Z   : 64 KiB @ 167772160
    const size_t MB32 = 33554432;
    __hip_bfloat16* q   = (__hip_bfloat16*)(ws);
    __hip_bfloat16* k   = (__hip_bfloat16*)(ws + MB32);
    __hip_bfloat16* vT  = (__hip_bfloat16*)(ws + 2 * MB32);
    __hip_bfloat16* P   = (__hip_bfloat16*)(ws + 3 * MB32);
    float*          Z   = (float*)(ws + 3 * MB32 + (size_t)67108864);
    short*          seqb = (short*)P;
    short*          Wb   = (short*)((char*)P + MB32);

    hipMemsetAsync(Z, 0, (size_t)BB * TT * sizeof(float), stream);

    cvt_all<<<9728, 256, 0, stream>>>(seq, Wq, Wk, Wv, seqb, Wb);
    qkv256<<<768, 512, 0, stream>>>(seqb, Wb, bq, bk, bv, q, k, vT);
    score256<<<BB * 64, 512, 0, stream>>>(q, k, P, Z);
    pv256<<<BB * 32, 512, 0, stream>>>(P, vT, Z, out);
}